// Round 7
// baseline (4301.204 us; speedup 1.0000x reference)
//
#include <hip/hip_runtime.h>

// ---------- types ----------
typedef __attribute__((ext_vector_type(8))) short short8;   // 8 bf16 (4 VGPRs)
typedef __attribute__((ext_vector_type(4))) float f32x4;    // MFMA accumulator

__device__ __forceinline__ unsigned short f2bf(float f) {
  union { float f; unsigned u; } x{f};
  unsigned r = x.u + 0x7FFFu + ((x.u >> 16) & 1u);  // round-to-nearest-even
  return (unsigned short)(r >> 16);
}

// async global->LDS, 16B per lane; LDS dest is wave-uniform base + lane*16
__device__ __forceinline__ void gload_lds16(const void* g, void* l) {
  __builtin_amdgcn_global_load_lds(
      (__attribute__((address_space(1))) void*)((unsigned long long)g),
      (__attribute__((address_space(3))) void*)(unsigned)((unsigned long long)l),
      16, 0, 0);
}

// 6-stage H64 butterfly over the first index of tile[64][64]
__device__ __forceinline__ void butterfly64(float (*tile)[64], int t) {
  const int c  = t & 63;
  const int pb = t >> 6;
#pragma unroll
  for (int h = 1; h < 64; h <<= 1) {
#pragma unroll
    for (int k = 0; k < 8; ++k) {
      const int p  = pb + (k << 2);
      const int j1 = ((p & ~(h - 1)) << 1) | (p & (h - 1));
      const int j2 = j1 + h;
      const float a = tile[j1][c], b = tile[j2][c];
      tile[j1][c] = a + b;
      tile[j2][c] = a - b;
    }
    __syncthreads();
  }
}

// ---------- K1: fused trellis decode + col-FWHT(low 6 bits of o) -> W[4096][4096] ----------
__global__ void k_deq_col1(const int* __restrict__ trellis,
                           const float* __restrict__ tlut,
                           float* __restrict__ W) {
  __shared__ unsigned short words[16][32];   // 16 tiles * 32 words
  __shared__ float tile[64][64];
  const int t  = threadIdx.x;
  const int rg = blockIdx.x >> 6;            // o-group (64 rows)
  const int cg = blockIdx.x & 63;            // i-group (64 cols)
#pragma unroll
  for (int r = 0; r < 2; ++r) {
    const int ff = t + (r << 8);
    const int a = ff >> 7, rw = ff & 127;
    const int src = ((rg * 4 + a) * 256 + cg * 4) * 32 + rw;
    ((unsigned short*)words)[a * 128 + rw] = (unsigned short)(trellis[src] & 0xFFFF);
  }
  __syncthreads();
#pragma unroll
  for (int r = 0; r < 8; ++r) {
    const int f  = t + (r << 8);
    const int tl = f >> 7, s = f & 127;
    const unsigned short* w = words[tl];
    unsigned state = 0;
#pragma unroll
    for (int j = 0; j < 4; ++j) {
      const int ss = (s - j) & 127;
      state |= (((unsigned)w[ss >> 2] >> (12 - 4 * (ss & 3))) & 0xFu) << (4 * j);
    }
    const float2 v = *(const float2*)(tlut + (size_t)state * 2);
    const int o = ((tl >> 2) << 4) + (s >> 3);
    const int i = ((tl & 3) << 4) + ((s & 7) << 1);
    tile[o][i]     = v.x;
    tile[o][i + 1] = v.y;
  }
  __syncthreads();
  butterfly64(tile, t);
  const size_t base = ((size_t)(rg * 64)) * 4096 + cg * 64;
#pragma unroll
  for (int k = 0; k < 4; ++k) {
    const int idx = t + (k << 8);
    const int r = idx >> 4, c4 = idx & 15;
    *(float4*)(W + base + (size_t)r * 4096 + (c4 << 2)) = *(float4*)(&tile[r][c4 << 2]);
  }
}

// ---------- K2: FWHT over rows (i axis, full H4096), in place, * 1/64 ----------
__global__ void k_fwht_row(float* __restrict__ W) {
  __shared__ float row[4096];
  const int t = threadIdx.x;
  float* g = W + ((size_t)blockIdx.x << 12);
#pragma unroll
  for (int k = 0; k < 4; ++k) {
    const int e = (t + (k << 8)) << 2;
    *(float4*)(row + e) = *(const float4*)(g + e);
  }
  __syncthreads();
  for (int h = 1; h < 4096; h <<= 1) {
#pragma unroll
    for (int k = 0; k < 8; ++k) {
      const int p  = t + (k << 8);
      const int j1 = ((p & ~(h - 1)) << 1) | (p & (h - 1));
      const int j2 = j1 + h;
      const float a = row[j1], b = row[j2];
      row[j1] = a + b;
      row[j2] = a - b;
    }
    __syncthreads();
  }
#pragma unroll
  for (int k = 0; k < 4; ++k) {
    const int e = (t + (k << 8)) << 2;
    float4 v = *(float4*)(row + e);
    v.x *= 0.015625f; v.y *= 0.015625f; v.z *= 0.015625f; v.w *= 0.015625f;
    *(float4*)(g + e) = v;
  }
}

// ---------- K3: col FWHT, high 6 bits of o, *1/64, *SV[o]*SU[i], -> bf16 Mt[N][K] ----------
__global__ void k_fwht_col2(const float* __restrict__ W,
                            const float* __restrict__ SU,
                            const float* __restrict__ SV,
                            unsigned short* __restrict__ Mt) {
  __shared__ float tile[64][64];
  const int t  = threadIdx.x;
  const int b  = blockIdx.x >> 6;   // row residue (low bits)
  const int cg = blockIdx.x & 63;
#pragma unroll
  for (int k = 0; k < 4; ++k) {
    const int idx = t + (k << 8);
    const int a = idx >> 4, c4 = idx & 15;
    const int row = (a << 6) + b;
    *(float4*)(&tile[a][c4 << 2]) =
        *(const float4*)(W + (size_t)row * 4096 + ((size_t)cg << 6) + (c4 << 2));
  }
  __syncthreads();
  butterfly64(tile, t);
#pragma unroll
  for (int k = 0; k < 4; ++k) {
    const int idx = t + (k << 8);
    const int a = idx >> 4, c4 = idx & 15;
    const int row = (a << 6) + b;                 // o (OUT index)
    const int col0 = (cg << 6) + (c4 << 2);       // i (IN index)
    const float sv = SV[row] * 0.015625f;
    const float4 su = *(const float4*)(SU + col0);
    const float4 v = *(float4*)(&tile[a][c4 << 2]);
    ushort4 o;
    o.x = f2bf(v.x * sv * su.x);
    o.y = f2bf(v.y * sv * su.y);
    o.z = f2bf(v.z * sv * su.z);
    o.w = f2bf(v.w * sv * su.w);
    *(ushort4*)(Mt + (size_t)row * 4096 + col0) = o;
  }
}

// ---------- K4: x fp32 -> bf16 ----------
__global__ void k_cvt_x(const float* __restrict__ x, unsigned short* __restrict__ xb) {
  const long long n4 = (long long)16384 * 4096 / 4;
  long long i = (long long)blockIdx.x * blockDim.x + threadIdx.x;
  const long long stride = (long long)gridDim.x * blockDim.x;
  for (; i < n4; i += stride) {
    const float4 v = *(const float4*)(x + i * 4);
    ushort4 o;
    o.x = f2bf(v.x); o.y = f2bf(v.y); o.z = f2bf(v.z); o.w = f2bf(v.w);
    *(ushort4*)(xb + i * 4) = o;
  }
}

// ---------- K5: 512x256 GEMM, 128x128 per-wave tiles, BK=32, free-run ----------
// LDS-port floor is the measured invariant (54% MfmaUtil across 3 schedules):
// ds_read bytes/FLOP = 1/tm + 1/tn. Wave tiles 128x64 -> 128x128 cuts LDS reads
// 33%/FLOP and staging 25%/FLOP. 8 waves in 4Mx2N grid; block 512x256; BK=32;
// LDS 96 KiB = A[2][512][32] + B[2][256][32] bf16, double-buffered.
// Swizzle (4 chunks/row): stored[row][c] = global[row][c ^ (row&3)] via
// pre-swizzled SOURCE (LDS dest linear = base+16*lane, required by
// global_load_lds); read XOR chunk = q ^ (lr&3). Verified: 64 lanes -> 2 per
// bank-quad (free). Free-run tile: vmcnt(0) (drains prev tile's 6 stages,
// landed long ago) + 1 barrier, stage next tile, 16 ds_read_b128, 64 MFMA.
#define BARRIER __builtin_amdgcn_s_barrier()
#define WAITV0  asm volatile("s_waitcnt vmcnt(0)" ::: "memory")

#define STAGE_ALL(db, jj) do { \
  const unsigned short* aJ = aRow + ((jj) << 5); \
  const unsigned short* bJ = bRow + ((jj) << 5); \
  gload_lds16(aJ,                  smem +         (db)*32768 +         w1k); \
  gload_lds16(aJ + (128ull << 12), smem +         (db)*32768 +  8192 + w1k); \
  gload_lds16(aJ + (256ull << 12), smem +         (db)*32768 + 16384 + w1k); \
  gload_lds16(aJ + (384ull << 12), smem +         (db)*32768 + 24576 + w1k); \
  gload_lds16(bJ,                  smem + 65536 + (db)*16384 +         w1k); \
  gload_lds16(bJ + (128ull << 12), smem + 65536 + (db)*16384 +  8192 + w1k); \
} while (0)

#define RD_A(base) do { _Pragma("unroll") \
  for (int mi = 0; mi < 8; ++mi) af[mi] = *(const short8*)((base) + mi*1024 + cx); } while (0)
#define RD_B(base) do { _Pragma("unroll") \
  for (int ni = 0; ni < 8; ++ni) bb[ni] = *(const short8*)((base) + ni*1024 + cx); } while (0)

#define MMA_ALL do { _Pragma("unroll") \
  for (int mi = 0; mi < 8; ++mi) { _Pragma("unroll") \
    for (int ni = 0; ni < 8; ++ni) \
      acc[mi][ni] = __builtin_amdgcn_mfma_f32_16x16x32_bf16(af[mi], bb[ni], acc[mi][ni], 0, 0, 0); \
  } } while (0)

#define KTILE(Asx, Bsx, STAGES) do { \
  WAITV0; BARRIER; \
  STAGES; \
  RD_B(Bsx); RD_A(Asx); \
  __builtin_amdgcn_s_setprio(1); MMA_ALL; __builtin_amdgcn_s_setprio(0); \
} while (0)

__global__ void __launch_bounds__(512, 2)
k_gemm8(const unsigned short* __restrict__ A,
        const unsigned short* __restrict__ B,
        float* __restrict__ C) {
  extern __shared__ char smem[];
  const int t    = threadIdx.x;
  const int lane = t & 63, w = t >> 6;
  const int wr   = w >> 1, wc = w & 1;          // 4M x 2N wave grid
  const int lr   = lane & 15, q = lane >> 4;
  const int w1k  = w * 1024;

  const int nt = blockIdx.x & 15;               // 16 N-tiles (256 each)
  const int mt = blockIdx.x >> 4;               // 32 M-tiles (512 each)

  // frag read offset within a [128][32] region: row*64 + (q^(row&3))*16; row=mi*16+lr
  const int cx = lr * 64 + ((q ^ (lr & 3)) << 4);

  // LDS read bases
  const char* As0 = smem +         wr * 8192;            // A dbuf0, 128-row slice wr
  const char* As1 = smem + 32768 + wr * 8192;            // A dbuf1
  const char* Bs0 = smem + 65536 +         wc * 8192;    // B dbuf0, 128-row slice wc
  const char* Bs1 = smem + 65536 + 16384 + wc * 8192;    // B dbuf1

  // staging source: row = t>>2 (plus 128*i per inst), chunk pre-swizzled c^(row&3)
  const int srow  = t >> 2;
  const int csrc8 = (((t & 3) ^ (srow & 3)) << 3);
  const unsigned short* aRow = A + (((size_t)(mt * 512 + srow)) << 12) + csrc8;
  const unsigned short* bRow = B + (((size_t)(nt * 256 + srow)) << 12) + csrc8;

  short8 af[8], bb[8];
  f32x4  acc[8][8];
#pragma unroll
  for (int i = 0; i < 8; ++i)
#pragma unroll
    for (int j = 0; j < 8; ++j) acc[i][j] = (f32x4){0.f, 0.f, 0.f, 0.f};

  // prologue: stage K-tile 0 into dbuf0
  STAGE_ALL(0, 0);

  for (int g = 0; g < 63; ++g) {
    KTILE(As0, Bs0, STAGE_ALL(1, 2 * g + 1));   // compute tile 2g,   stage 2g+1
    KTILE(As1, Bs1, STAGE_ALL(0, 2 * g + 2));   // compute tile 2g+1, stage 2g+2
  }
  KTILE(As0, Bs0, STAGE_ALL(1, 127));           // compute tile 126, stage 127
  KTILE(As1, Bs1, {});                          // compute tile 127

  // epilogue: C/D layout col=lane&15, row=(lane>>4)*4+reg
  float* cbase = C + (((size_t)(mt * 512 + wr * 128 + q * 4)) << 12)
               + nt * 256 + wc * 128 + lr;
#pragma unroll
  for (int mi = 0; mi < 8; ++mi)
#pragma unroll
    for (int ni = 0; ni < 8; ++ni)
#pragma unroll
      for (int r = 0; r < 4; ++r)
        cbase[(((size_t)(mi * 16 + r)) << 12) + ni * 16] = acc[mi][ni][r];
}

extern "C" void kernel_launch(void* const* d_in, const int* in_sizes, int n_in,
                              void* d_out, int out_size, void* d_ws, size_t ws_size,
                              hipStream_t stream) {
  const float* x       = (const float*)d_in[0];   // (8,2048,4096) fp32
  const int*   trellis = (const int*)d_in[1];     // (65536,32) int32
  const float* tlut    = (const float*)d_in[2];   // (65536,2) fp32
  const float* SU      = (const float*)d_in[3];   // (4096,)
  const float* SV      = (const float*)d_in[4];   // (4096,)
  float* out = (float*)d_out;

  char* ws = (char*)d_ws;
  float*          W  = (float*)ws;                            // 64 MiB fp32
  unsigned short* Mt = (unsigned short*)(ws + (64ull << 20)); // 32 MiB bf16 [N][K]
  unsigned short* xb = (unsigned short*)(ws + (96ull << 20)); // 128 MiB bf16 [M][K]

  hipFuncSetAttribute(reinterpret_cast<const void*>(&k_gemm8),
                      hipFuncAttributeMaxDynamicSharedMemorySize, 98304);

  hipLaunchKernelGGL(k_deq_col1,  dim3(4096),  dim3(256), 0, stream, trellis, tlut, W);
  hipLaunchKernelGGL(k_fwht_row,  dim3(4096),  dim3(256), 0, stream, W);
  hipLaunchKernelGGL(k_fwht_col2, dim3(4096),  dim3(256), 0, stream, W, SU, SV, Mt);
  hipLaunchKernelGGL(k_cvt_x,     dim3(2048),  dim3(256), 0, stream, x, xb);
  hipLaunchKernelGGL(k_gemm8,     dim3(512),   dim3(512), 98304, stream, xb, Mt, out);
}

// Round 8
// 691.507 us; speedup vs baseline: 6.2200x; 6.2200x over previous
//
#include <hip/hip_runtime.h>

// ---------- types ----------
typedef __attribute__((ext_vector_type(8))) short short8;   // 8 bf16 (4 VGPRs)
typedef __attribute__((ext_vector_type(4))) float f32x4;    // MFMA accumulator

__device__ __forceinline__ unsigned short f2bf(float f) {
  union { float f; unsigned u; } x{f};
  unsigned r = x.u + 0x7FFFu + ((x.u >> 16) & 1u);  // round-to-nearest-even
  return (unsigned short)(r >> 16);
}

// async global->LDS, 16B per lane; LDS dest is wave-uniform base + lane*16
__device__ __forceinline__ void gload_lds16(const void* g, void* l) {
  __builtin_amdgcn_global_load_lds(
      (__attribute__((address_space(1))) void*)((unsigned long long)g),
      (__attribute__((address_space(3))) void*)(unsigned)((unsigned long long)l),
      16, 0, 0);
}

// 6-stage H64 butterfly over the first index of tile[64][64]
__device__ __forceinline__ void butterfly64(float (*tile)[64], int t) {
  const int c  = t & 63;
  const int pb = t >> 6;
#pragma unroll
  for (int h = 1; h < 64; h <<= 1) {
#pragma unroll
    for (int k = 0; k < 8; ++k) {
      const int p  = pb + (k << 2);
      const int j1 = ((p & ~(h - 1)) << 1) | (p & (h - 1));
      const int j2 = j1 + h;
      const float a = tile[j1][c], b = tile[j2][c];
      tile[j1][c] = a + b;
      tile[j2][c] = a - b;
    }
    __syncthreads();
  }
}

// ---------- K1: fused trellis decode + col-FWHT(low 6 bits of o) -> W[4096][4096] ----------
__global__ void k_deq_col1(const int* __restrict__ trellis,
                           const float* __restrict__ tlut,
                           float* __restrict__ W) {
  __shared__ unsigned short words[16][32];   // 16 tiles * 32 words
  __shared__ float tile[64][64];
  const int t  = threadIdx.x;
  const int rg = blockIdx.x >> 6;            // o-group (64 rows)
  const int cg = blockIdx.x & 63;            // i-group (64 cols)
#pragma unroll
  for (int r = 0; r < 2; ++r) {
    const int ff = t + (r << 8);
    const int a = ff >> 7, rw = ff & 127;
    const int src = ((rg * 4 + a) * 256 + cg * 4) * 32 + rw;
    ((unsigned short*)words)[a * 128 + rw] = (unsigned short)(trellis[src] & 0xFFFF);
  }
  __syncthreads();
#pragma unroll
  for (int r = 0; r < 8; ++r) {
    const int f  = t + (r << 8);
    const int tl = f >> 7, s = f & 127;
    const unsigned short* w = words[tl];
    unsigned state = 0;
#pragma unroll
    for (int j = 0; j < 4; ++j) {
      const int ss = (s - j) & 127;
      state |= (((unsigned)w[ss >> 2] >> (12 - 4 * (ss & 3))) & 0xFu) << (4 * j);
    }
    const float2 v = *(const float2*)(tlut + (size_t)state * 2);
    const int o = ((tl >> 2) << 4) + (s >> 3);
    const int i = ((tl & 3) << 4) + ((s & 7) << 1);
    tile[o][i]     = v.x;
    tile[o][i + 1] = v.y;
  }
  __syncthreads();
  butterfly64(tile, t);
  const size_t base = ((size_t)(rg * 64)) * 4096 + cg * 64;
#pragma unroll
  for (int k = 0; k < 4; ++k) {
    const int idx = t + (k << 8);
    const int r = idx >> 4, c4 = idx & 15;
    *(float4*)(W + base + (size_t)r * 4096 + (c4 << 2)) = *(float4*)(&tile[r][c4 << 2]);
  }
}

// ---------- K2: FWHT over rows (i axis, full H4096), in place, * 1/64 ----------
__global__ void k_fwht_row(float* __restrict__ W) {
  __shared__ float row[4096];
  const int t = threadIdx.x;
  float* g = W + ((size_t)blockIdx.x << 12);
#pragma unroll
  for (int k = 0; k < 4; ++k) {
    const int e = (t + (k << 8)) << 2;
    *(float4*)(row + e) = *(const float4*)(g + e);
  }
  __syncthreads();
  for (int h = 1; h < 4096; h <<= 1) {
#pragma unroll
    for (int k = 0; k < 8; ++k) {
      const int p  = t + (k << 8);
      const int j1 = ((p & ~(h - 1)) << 1) | (p & (h - 1));
      const int j2 = j1 + h;
      const float a = row[j1], b = row[j2];
      row[j1] = a + b;
      row[j2] = a - b;
    }
    __syncthreads();
  }
#pragma unroll
  for (int k = 0; k < 4; ++k) {
    const int e = (t + (k << 8)) << 2;
    float4 v = *(float4*)(row + e);
    v.x *= 0.015625f; v.y *= 0.015625f; v.z *= 0.015625f; v.w *= 0.015625f;
    *(float4*)(g + e) = v;
  }
}

// ---------- K3: col FWHT, high 6 bits of o, *1/64, *SV[o]*SU[i], -> bf16 Mt[N][K] ----------
__global__ void k_fwht_col2(const float* __restrict__ W,
                            const float* __restrict__ SU,
                            const float* __restrict__ SV,
                            unsigned short* __restrict__ Mt) {
  __shared__ float tile[64][64];
  const int t  = threadIdx.x;
  const int b  = blockIdx.x >> 6;   // row residue (low bits)
  const int cg = blockIdx.x & 63;
#pragma unroll
  for (int k = 0; k < 4; ++k) {
    const int idx = t + (k << 8);
    const int a = idx >> 4, c4 = idx & 15;
    const int row = (a << 6) + b;
    *(float4*)(&tile[a][c4 << 2]) =
        *(const float4*)(W + (size_t)row * 4096 + ((size_t)cg << 6) + (c4 << 2));
  }
  __syncthreads();
  butterfly64(tile, t);
#pragma unroll
  for (int k = 0; k < 4; ++k) {
    const int idx = t + (k << 8);
    const int a = idx >> 4, c4 = idx & 15;
    const int row = (a << 6) + b;                 // o (OUT index)
    const int col0 = (cg << 6) + (c4 << 2);       // i (IN index)
    const float sv = SV[row] * 0.015625f;
    const float4 su = *(const float4*)(SU + col0);
    const float4 v = *(float4*)(&tile[a][c4 << 2]);
    ushort4 o;
    o.x = f2bf(v.x * sv * su.x);
    o.y = f2bf(v.y * sv * su.y);
    o.z = f2bf(v.z * sv * su.z);
    o.w = f2bf(v.w * sv * su.w);
    *(ushort4*)(Mt + (size_t)row * 4096 + col0) = o;
  }
}

// ---------- K4: x fp32 -> bf16 ----------
__global__ void k_cvt_x(const float* __restrict__ x, unsigned short* __restrict__ xb) {
  const long long n4 = (long long)16384 * 4096 / 4;
  long long i = (long long)blockIdx.x * blockDim.x + threadIdx.x;
  const long long stride = (long long)gridDim.x * blockDim.x;
  for (; i < n4; i += stride) {
    const float4 v = *(const float4*)(x + i * 4);
    ushort4 o;
    o.x = f2bf(v.x); o.y = f2bf(v.y); o.z = f2bf(v.z); o.w = f2bf(v.w);
    *(ushort4*)(xb + i * 4) = o;
  }
}

// ---------- K5: 256x256 GEMM, free-run K-tiles + DE-BURST pipelined reads ----------
// R6 geometry (proven no-spill: 128x64 wave tiles, acc[8][4], BK=64, 128KiB LDS).
// Changes vs R6:
//  (1) A-frag reads software-pipelined INSIDE the MFMA stream (read mi+1 while
//      row mi's 4 MFMAs run) -> each wave trickles ds_reads into the CU port at
//      consumption rate instead of a 24-read post-barrier burst.
//  (2) no setprio (m190: hurts GEMM without wave role-split).
//  (3) bijective XCD swizzle: nwg=1024=8*128, swz=(bid&7)*128+(bid>>3) ->
//      each XCD owns an 8-mt slab, nt-fastest keeps the 2MB A-panel L2-local.
#define BARRIER __builtin_amdgcn_s_barrier()
#define WAITV0  asm volatile("s_waitcnt vmcnt(0)" ::: "memory")

#define STAGE_ALL(db, jj) do { \
  const unsigned short* aJ = aRow + ((jj) << 6); \
  const unsigned short* bJ = bRow + ((jj) << 6); \
  gload_lds16(aJ,                  smem +         (db)*32768 +         w1k); \
  gload_lds16(aJ + ( 64ull << 12), smem +         (db)*32768 +  8192 + w1k); \
  gload_lds16(aJ + (128ull << 12), smem +         (db)*32768 + 16384 + w1k); \
  gload_lds16(aJ + (192ull << 12), smem +         (db)*32768 + 24576 + w1k); \
  gload_lds16(bJ,                  smem + 65536 + (db)*32768 +         w1k); \
  gload_lds16(bJ + ( 64ull << 12), smem + 65536 + (db)*32768 +  8192 + w1k); \
  gload_lds16(bJ + (128ull << 12), smem + 65536 + (db)*32768 + 16384 + w1k); \
  gload_lds16(bJ + (192ull << 12), smem + 65536 + (db)*32768 + 24576 + w1k); \
} while (0)

// one K=32 half: 4 B-reads, then rolling {read A(mi+1) || 4 MFMA on A(mi)}
#define HALF_K(Asx, Bsx, cx) do { \
  bb[0] = *(const short8*)((Bsx) + 0*2048 + (cx)); \
  bb[1] = *(const short8*)((Bsx) + 1*2048 + (cx)); \
  bb[2] = *(const short8*)((Bsx) + 2*2048 + (cx)); \
  bb[3] = *(const short8*)((Bsx) + 3*2048 + (cx)); \
  short8 acur = *(const short8*)((Asx) + 0*2048 + (cx)); \
  _Pragma("unroll") \
  for (int mi = 0; mi < 8; ++mi) { \
    short8 anxt = acur; \
    if (mi < 7) anxt = *(const short8*)((Asx) + (mi + 1) * 2048 + (cx)); \
    acc[mi][0] = __builtin_amdgcn_mfma_f32_16x16x32_bf16(acur, bb[0], acc[mi][0], 0, 0, 0); \
    acc[mi][1] = __builtin_amdgcn_mfma_f32_16x16x32_bf16(acur, bb[1], acc[mi][1], 0, 0, 0); \
    acc[mi][2] = __builtin_amdgcn_mfma_f32_16x16x32_bf16(acur, bb[2], acc[mi][2], 0, 0, 0); \
    acc[mi][3] = __builtin_amdgcn_mfma_f32_16x16x32_bf16(acur, bb[3], acc[mi][3], 0, 0, 0); \
    acur = anxt; \
  } \
} while (0)

#define KTILE(Asx, Bsx, STAGES) do { \
  WAITV0; BARRIER; \
  STAGES; \
  HALF_K(Asx, Bsx, cx0); \
  HALF_K(Asx, Bsx, cx1); \
} while (0)

__global__ void __launch_bounds__(512, 2)
k_gemm8(const unsigned short* __restrict__ A,
        const unsigned short* __restrict__ B,
        float* __restrict__ C) {
  extern __shared__ char smem[];
  const int t    = threadIdx.x;
  const int lane = t & 63, w = t >> 6;
  const int wr   = w >> 2, wc = w & 3;          // 2 x 4 wave grid
  const int hb   = wc >> 1, rb = (wc & 1) * 64; // B half / row base within half
  const int lr   = lane & 15, q = lane >> 4;
  const int w1k  = w * 1024;

  // bijective XCD swizzle: 1024 blocks = 8 XCDs x 128 contiguous
  const int bid = ((blockIdx.x & 7) << 7) + (blockIdx.x >> 3);
  const int nt  = bid & 15;                     // 16 N-tiles (nt-fastest in-XCD)
  const int mt  = bid >> 4;                     // 64 M-tiles

  // frag read offsets (bytes within a [128][64] half): row*128 + (chunk^(row&7))*16
  const int cx0 = lr * 128 + (((0 + q) ^ (lr & 7)) << 4);
  const int cx1 = lr * 128 + (((4 + q) ^ (lr & 7)) << 4);

  // LDS read bases (A halves [2][128][64] per dbuf @0, B @64KiB)
  const char* As0 = smem +         wr * 16384;            // A dbuf0, half=wr
  const char* As1 = smem + 32768 + wr * 16384;            // A dbuf1
  const char* Bs0 = smem + 65536 +         hb * 16384 + rb * 128;
  const char* Bs1 = smem + 65536 + 32768 + hb * 16384 + rb * 128;

  // staging source: row = (t>>3) within 64-row sub, chunk pre-swizzled c^(row&7)
  const int srow  = t >> 3;
  const int csrc8 = (((t & 7) ^ (srow & 7)) << 3);
  const unsigned short* aRow = A + (((size_t)(mt * 256 + srow)) << 12) + csrc8;
  const unsigned short* bRow = B + (((size_t)(nt * 256 + srow)) << 12) + csrc8;

  short8 bb[4];
  f32x4  acc[8][4];
#pragma unroll
  for (int i = 0; i < 8; ++i)
#pragma unroll
    for (int j = 0; j < 4; ++j) acc[i][j] = (f32x4){0.f, 0.f, 0.f, 0.f};

  // prologue: stage K-tile 0 into dbuf0
  STAGE_ALL(0, 0);

  for (int g = 0; g < 31; ++g) {
    KTILE(As0, Bs0, STAGE_ALL(1, 2 * g + 1));   // compute tile 2g,   stage 2g+1
    KTILE(As1, Bs1, STAGE_ALL(0, 2 * g + 2));   // compute tile 2g+1, stage 2g+2
  }
  KTILE(As0, Bs0, STAGE_ALL(1, 63));            // compute tile 62, stage 63
  KTILE(As1, Bs1, {});                          // compute tile 63

  // epilogue: C/D layout col=lane&15, row=(lane>>4)*4+reg
  float* cbase = C + (((size_t)(mt * 256 + wr * 128 + q * 4)) << 12)
               + nt * 256 + wc * 64 + lr;
#pragma unroll
  for (int mi = 0; mi < 8; ++mi)
#pragma unroll
    for (int ni = 0; ni < 4; ++ni)
#pragma unroll
      for (int r = 0; r < 4; ++r)
        cbase[(((size_t)(mi * 16 + r)) << 12) + ni * 16] = acc[mi][ni][r];
}

extern "C" void kernel_launch(void* const* d_in, const int* in_sizes, int n_in,
                              void* d_out, int out_size, void* d_ws, size_t ws_size,
                              hipStream_t stream) {
  const float* x       = (const float*)d_in[0];   // (8,2048,4096) fp32
  const int*   trellis = (const int*)d_in[1];     // (65536,32) int32
  const float* tlut    = (const float*)d_in[2];   // (65536,2) fp32
  const float* SU      = (const float*)d_in[3];   // (4096,)
  const float* SV      = (const float*)d_in[4];   // (4096,)
  float* out = (float*)d_out;

  char* ws = (char*)d_ws;
  float*          W  = (float*)ws;                            // 64 MiB fp32
  unsigned short* Mt = (unsigned short*)(ws + (64ull << 20)); // 32 MiB bf16 [N][K]
  unsigned short* xb = (unsigned short*)(ws + (96ull << 20)); // 128 MiB bf16 [M][K]

  hipFuncSetAttribute(reinterpret_cast<const void*>(&k_gemm8),
                      hipFuncAttributeMaxDynamicSharedMemorySize, 131072);

  hipLaunchKernelGGL(k_deq_col1,  dim3(4096),  dim3(256), 0, stream, trellis, tlut, W);
  hipLaunchKernelGGL(k_fwht_row,  dim3(4096),  dim3(256), 0, stream, W);
  hipLaunchKernelGGL(k_fwht_col2, dim3(4096),  dim3(256), 0, stream, W, SU, SV, Mt);
  hipLaunchKernelGGL(k_cvt_x,     dim3(2048),  dim3(256), 0, stream, x, xb);
  hipLaunchKernelGGL(k_gemm8,     dim3(1024),  dim3(512), 131072, stream, xb, Mt, out);
}

// Round 9
// 674.320 us; speedup vs baseline: 6.3786x; 1.0255x over previous
//
#include <hip/hip_runtime.h>

// ---------- types ----------
typedef __attribute__((ext_vector_type(8))) short short8;    // 8 bf16 (4 VGPRs)
typedef __attribute__((ext_vector_type(16))) float f32x16;   // 32x32 MFMA accumulator

__device__ __forceinline__ unsigned short f2bf(float f) {
  union { float f; unsigned u; } x{f};
  unsigned r = x.u + 0x7FFFu + ((x.u >> 16) & 1u);  // round-to-nearest-even
  return (unsigned short)(r >> 16);
}

// async global->LDS, 16B per lane; LDS dest is wave-uniform base + lane*16
__device__ __forceinline__ void gload_lds16(const void* g, void* l) {
  __builtin_amdgcn_global_load_lds(
      (__attribute__((address_space(1))) void*)((unsigned long long)g),
      (__attribute__((address_space(3))) void*)(unsigned)((unsigned long long)l),
      16, 0, 0);
}

// 6-stage H64 butterfly over the first index of tile[64][64]
__device__ __forceinline__ void butterfly64(float (*tile)[64], int t) {
  const int c  = t & 63;
  const int pb = t >> 6;
#pragma unroll
  for (int h = 1; h < 64; h <<= 1) {
#pragma unroll
    for (int k = 0; k < 8; ++k) {
      const int p  = pb + (k << 2);
      const int j1 = ((p & ~(h - 1)) << 1) | (p & (h - 1));
      const int j2 = j1 + h;
      const float a = tile[j1][c], b = tile[j2][c];
      tile[j1][c] = a + b;
      tile[j2][c] = a - b;
    }
    __syncthreads();
  }
}

// ---------- K1: fused trellis decode + col-FWHT(low 6 bits of o) -> W[4096][4096] ----------
__global__ void k_deq_col1(const int* __restrict__ trellis,
                           const float* __restrict__ tlut,
                           float* __restrict__ W) {
  __shared__ unsigned short words[16][32];   // 16 tiles * 32 words
  __shared__ float tile[64][64];
  const int t  = threadIdx.x;
  const int rg = blockIdx.x >> 6;            // o-group (64 rows)
  const int cg = blockIdx.x & 63;            // i-group (64 cols)
#pragma unroll
  for (int r = 0; r < 2; ++r) {
    const int ff = t + (r << 8);
    const int a = ff >> 7, rw = ff & 127;
    const int src = ((rg * 4 + a) * 256 + cg * 4) * 32 + rw;
    ((unsigned short*)words)[a * 128 + rw] = (unsigned short)(trellis[src] & 0xFFFF);
  }
  __syncthreads();
#pragma unroll
  for (int r = 0; r < 8; ++r) {
    const int f  = t + (r << 8);
    const int tl = f >> 7, s = f & 127;
    const unsigned short* w = words[tl];
    unsigned state = 0;
#pragma unroll
    for (int j = 0; j < 4; ++j) {
      const int ss = (s - j) & 127;
      state |= (((unsigned)w[ss >> 2] >> (12 - 4 * (ss & 3))) & 0xFu) << (4 * j);
    }
    const float2 v = *(const float2*)(tlut + (size_t)state * 2);
    const int o = ((tl >> 2) << 4) + (s >> 3);
    const int i = ((tl & 3) << 4) + ((s & 7) << 1);
    tile[o][i]     = v.x;
    tile[o][i + 1] = v.y;
  }
  __syncthreads();
  butterfly64(tile, t);
  const size_t base = ((size_t)(rg * 64)) * 4096 + cg * 64;
#pragma unroll
  for (int k = 0; k < 4; ++k) {
    const int idx = t + (k << 8);
    const int r = idx >> 4, c4 = idx & 15;
    *(float4*)(W + base + (size_t)r * 4096 + (c4 << 2)) = *(float4*)(&tile[r][c4 << 2]);
  }
}

// ---------- K2: FWHT over rows (i axis, full H4096), in place, * 1/64 ----------
__global__ void k_fwht_row(float* __restrict__ W) {
  __shared__ float row[4096];
  const int t = threadIdx.x;
  float* g = W + ((size_t)blockIdx.x << 12);
#pragma unroll
  for (int k = 0; k < 4; ++k) {
    const int e = (t + (k << 8)) << 2;
    *(float4*)(row + e) = *(const float4*)(g + e);
  }
  __syncthreads();
  for (int h = 1; h < 4096; h <<= 1) {
#pragma unroll
    for (int k = 0; k < 8; ++k) {
      const int p  = t + (k << 8);
      const int j1 = ((p & ~(h - 1)) << 1) | (p & (h - 1));
      const int j2 = j1 + h;
      const float a = row[j1], b = row[j2];
      row[j1] = a + b;
      row[j2] = a - b;
    }
    __syncthreads();
  }
#pragma unroll
  for (int k = 0; k < 4; ++k) {
    const int e = (t + (k << 8)) << 2;
    float4 v = *(float4*)(row + e);
    v.x *= 0.015625f; v.y *= 0.015625f; v.z *= 0.015625f; v.w *= 0.015625f;
    *(float4*)(g + e) = v;
  }
}

// ---------- K3: col FWHT, high 6 bits of o, *1/64, *SV[o]*SU[i], -> bf16 Mt[N][K] ----------
__global__ void k_fwht_col2(const float* __restrict__ W,
                            const float* __restrict__ SU,
                            const float* __restrict__ SV,
                            unsigned short* __restrict__ Mt) {
  __shared__ float tile[64][64];
  const int t  = threadIdx.x;
  const int b  = blockIdx.x >> 6;   // row residue (low bits)
  const int cg = blockIdx.x & 63;
#pragma unroll
  for (int k = 0; k < 4; ++k) {
    const int idx = t + (k << 8);
    const int a = idx >> 4, c4 = idx & 15;
    const int row = (a << 6) + b;
    *(float4*)(&tile[a][c4 << 2]) =
        *(const float4*)(W + (size_t)row * 4096 + ((size_t)cg << 6) + (c4 << 2));
  }
  __syncthreads();
  butterfly64(tile, t);
#pragma unroll
  for (int k = 0; k < 4; ++k) {
    const int idx = t + (k << 8);
    const int a = idx >> 4, c4 = idx & 15;
    const int row = (a << 6) + b;                 // o (OUT index)
    const int col0 = (cg << 6) + (c4 << 2);       // i (IN index)
    const float sv = SV[row] * 0.015625f;
    const float4 su = *(const float4*)(SU + col0);
    const float4 v = *(float4*)(&tile[a][c4 << 2]);
    ushort4 o;
    o.x = f2bf(v.x * sv * su.x);
    o.y = f2bf(v.y * sv * su.y);
    o.z = f2bf(v.z * sv * su.z);
    o.w = f2bf(v.w * sv * su.w);
    *(ushort4*)(Mt + (size_t)row * 4096 + col0) = o;
  }
}

// ---------- K4: x fp32 -> bf16 ----------
__global__ void k_cvt_x(const float* __restrict__ x, unsigned short* __restrict__ xb) {
  const long long n4 = (long long)16384 * 4096 / 4;
  long long i = (long long)blockIdx.x * blockDim.x + threadIdx.x;
  const long long stride = (long long)gridDim.x * blockDim.x;
  for (; i < n4; i += stride) {
    const float4 v = *(const float4*)(x + i * 4);
    ushort4 o;
    o.x = f2bf(v.x); o.y = f2bf(v.y); o.z = f2bf(v.z); o.w = f2bf(v.w);
    *(ushort4*)(xb + i * 4) = o;
  }
}

// ---------- K5: 256x256 8-phase GEMM with 32x32x16 MFMA ----------
// R3 skeleton (proven 474us: 8 phases / 2 K-tiles, same STAGE placement,
// vmcnt(4) at phases 4&8, setprio, 2 barriers/phase, 128KiB LDS) with the
// MFMA shape switched 16x16x32 -> 32x32x16 (ceiling 2075 -> 2495 TF, -17%
// matrix-pipe cycles/FLOP, half the MFMA issue slots, identical LDS bytes).
// Operand layout: A/B lane l holds row/col (l&31), k = (l>>5)*8..+8 (the
// verified 16x16 pattern generalized); C/D: col=lane&31,
// row=(reg&3)+8*(reg>>2)+4*(lane>>5)  [HW-measured m74/m101].
// Swizzle: frag rows mi*32+lr32 -> row&7 = lr32&7; chunk = 2*kk+l5;
// 8 lanes/bank-quad = minimum aliasing (conflict-free).
#define BARRIER __builtin_amdgcn_s_barrier()
#define WAITV4  asm volatile("s_waitcnt vmcnt(4)" ::: "memory")
#define WAITV0  asm volatile("s_waitcnt vmcnt(0)" ::: "memory")

#define STAGE_A(db, h, jj) do { \
  gload_lds16(aRow + (((size_t)((h)*128      )) << 12) + ((jj) << 6), smem +         (db)*32768 + (h)*16384 +        w1k); \
  gload_lds16(aRow + (((size_t)((h)*128 + 64 )) << 12) + ((jj) << 6), smem +         (db)*32768 + (h)*16384 + 8192 + w1k); \
} while (0)
#define STAGE_B(db, h, jj) do { \
  gload_lds16(bRow + (((size_t)((h)*128      )) << 12) + ((jj) << 6), smem + 65536 + (db)*32768 + (h)*16384 +        w1k); \
  gload_lds16(bRow + (((size_t)((h)*128 + 64 )) << 12) + ((jj) << 6), smem + 65536 + (db)*32768 + (h)*16384 + 8192 + w1k); \
} while (0)

// A frags: 4 mi-blocks x 2 k-chunks (one K=32 half-pair) = 8 ds_read_b128
#define RD_A2(base, cxa, cxb) do { _Pragma("unroll") \
  for (int mi = 0; mi < 4; ++mi) { \
    af[mi][0] = *(const short8*)((base) + mi*4096 + (cxa)); \
    af[mi][1] = *(const short8*)((base) + mi*4096 + (cxb)); \
  } } while (0)
// B frags for one 32-col block: 2 ds_read_b128
#define RD_B2(nb, base, cxa, cxb) do { \
  bb0 = *(const short8*)((base) + (nb)*4096 + (cxa)); \
  bb1 = *(const short8*)((base) + (nb)*4096 + (cxb)); } while (0)

// 8 MFMA: 4 mi x 2 k-steps into acc[mi][nb]
#define MMA8(nb) do { _Pragma("unroll") \
  for (int mi = 0; mi < 4; ++mi) { \
    acc[mi][nb] = __builtin_amdgcn_mfma_f32_32x32x16_bf16(af[mi][0], bb0, acc[mi][nb], 0, 0, 0); \
    acc[mi][nb] = __builtin_amdgcn_mfma_f32_32x32x16_bf16(af[mi][1], bb1, acc[mi][nb], 0, 0, 0); \
  } } while (0)

#define PHASE(READS, STAGE, WAIT, MMAC) do { \
  READS; STAGE; WAIT; \
  BARRIER; \
  __builtin_amdgcn_s_setprio(1); MMAC; __builtin_amdgcn_s_setprio(0); \
  BARRIER; \
} while (0)

__global__ void __launch_bounds__(512, 2)
k_gemm8(const unsigned short* __restrict__ A,
        const unsigned short* __restrict__ B,
        float* __restrict__ C) {
  extern __shared__ char smem[];
  const int t    = threadIdx.x;
  const int lane = t & 63, w = t >> 6;
  const int wr   = w >> 2, wc = w & 3;          // 2 x 4 wave grid (128x64 tiles)
  const int hb   = wc >> 1, rb = (wc & 1) * 64; // B half / 64-row base within half
  const int lr32 = lane & 31, l5 = lane >> 5;
  const int w1k  = w * 1024;

  const int nt = blockIdx.x & 15;               // 16 N-tiles
  const int mt = blockIdx.x >> 4;               // 64 M-tiles

  // frag read offsets (bytes in [128][64] half): row*128 + ((2*kk+l5)^(row&7))*16
  const int cxk0 = lr32 * 128 + (((0 + l5) ^ (lr32 & 7)) << 4);
  const int cxk1 = lr32 * 128 + (((2 + l5) ^ (lr32 & 7)) << 4);
  const int cxk2 = lr32 * 128 + (((4 + l5) ^ (lr32 & 7)) << 4);
  const int cxk3 = lr32 * 128 + (((6 + l5) ^ (lr32 & 7)) << 4);

  // LDS read bases
  const char* As0 = smem +         wr * 16384;            // A dbuf0, half=wr
  const char* As1 = smem + 32768 + wr * 16384;            // A dbuf1
  const char* Bs0 = smem + 65536 +         hb * 16384 + rb * 128;
  const char* Bs1 = smem + 65536 + 32768 + hb * 16384 + rb * 128;

  // staging source: row = (t>>3) within 64-row sub, chunk pre-swizzled c^(row&7)
  const int srow  = t >> 3;
  const int csrc8 = (((t & 7) ^ (srow & 7)) << 3);
  const unsigned short* aRow = A + (((size_t)(mt * 256 + srow)) << 12) + csrc8;
  const unsigned short* bRow = B + (((size_t)(nt * 256 + srow)) << 12) + csrc8;

  short8 af[4][2], bb0, bb1;
  f32x16 acc[4][2];
#pragma unroll
  for (int i = 0; i < 4; ++i)
#pragma unroll
    for (int j = 0; j < 2; ++j)
#pragma unroll
      for (int r = 0; r < 16; ++r) acc[i][j][r] = 0.f;

  // prologue: K-tile 0 (4 HTs) + A halves of K-tile 1
  STAGE_A(0, 0, 0); STAGE_A(0, 1, 0); STAGE_B(0, 0, 0); STAGE_B(0, 1, 0);
  STAGE_A(1, 0, 1); STAGE_A(1, 1, 1);
  WAITV4;           // K-tile 0 fully landed; A(1) may remain in flight
  BARRIER;

  for (int g = 0; g < 31; ++g) {
    const int j1 = 2 * g + 1, j2 = 2 * g + 2, j3 = 2 * g + 3;
    // ---- K-tile 2g from dbuf0 ----
    PHASE({ RD_A2(As0, cxk0, cxk1); RD_B2(0, Bs0, cxk0, cxk1); }, STAGE_B(1, 0, j1), ,       MMA8(0));
    PHASE({ RD_B2(1, Bs0, cxk0, cxk1); },                         STAGE_B(1, 1, j1), ,       MMA8(1));
    PHASE({ RD_A2(As0, cxk2, cxk3); RD_B2(0, Bs0, cxk2, cxk3); }, STAGE_A(0, 0, j2), ,       MMA8(0));
    PHASE({ RD_B2(1, Bs0, cxk2, cxk3); },                         STAGE_A(0, 1, j2), WAITV4, MMA8(1));
    // ---- K-tile 2g+1 from dbuf1 ----
    PHASE({ RD_A2(As1, cxk0, cxk1); RD_B2(0, Bs1, cxk0, cxk1); }, STAGE_B(0, 0, j2), ,       MMA8(0));
    PHASE({ RD_B2(1, Bs1, cxk0, cxk1); },                         STAGE_B(0, 1, j2), ,       MMA8(1));
    PHASE({ RD_A2(As1, cxk2, cxk3); RD_B2(0, Bs1, cxk2, cxk3); }, STAGE_A(1, 0, j3), ,       MMA8(0));
    PHASE({ RD_B2(1, Bs1, cxk2, cxk3); },                         STAGE_A(1, 1, j3), WAITV4, MMA8(1));
  }
  // ---- tail group g=31: K-tiles 62,63; only B(63) left to stage ----
  PHASE({ RD_A2(As0, cxk0, cxk1); RD_B2(0, Bs0, cxk0, cxk1); }, STAGE_B(1, 0, 63), ,       MMA8(0));
  PHASE({ RD_B2(1, Bs0, cxk0, cxk1); },                         STAGE_B(1, 1, 63), ,       MMA8(1));
  PHASE({ RD_A2(As0, cxk2, cxk3); RD_B2(0, Bs0, cxk2, cxk3); }, ,                  ,       MMA8(0));
  PHASE({ RD_B2(1, Bs0, cxk2, cxk3); },                         ,                  WAITV0, MMA8(1));
  PHASE({ RD_A2(As1, cxk0, cxk1); RD_B2(0, Bs1, cxk0, cxk1); }, ,                  ,       MMA8(0));
  PHASE({ RD_B2(1, Bs1, cxk0, cxk1); },                         ,                  ,       MMA8(1));
  PHASE({ RD_A2(As1, cxk2, cxk3); RD_B2(0, Bs1, cxk2, cxk3); }, ,                  ,       MMA8(0));
  PHASE({ RD_B2(1, Bs1, cxk2, cxk3); },                         ,                  ,       MMA8(1));

  // epilogue: C/D layout col=lane&31, row=(reg&3)+8*(reg>>2)+4*(lane>>5)
  float* cb = C + (((size_t)(mt * 256 + wr * 128 + l5 * 4)) << 12)
            + nt * 256 + wc * 64 + lr32;
#pragma unroll
  for (int mi = 0; mi < 4; ++mi)
#pragma unroll
    for (int nb = 0; nb < 2; ++nb)
#pragma unroll
      for (int r = 0; r < 16; ++r)
        cb[(((size_t)(mi * 32 + (r & 3) + 8 * (r >> 2))) << 12) + nb * 32] = acc[mi][nb][r];
}

extern "C" void kernel_launch(void* const* d_in, const int* in_sizes, int n_in,
                              void* d_out, int out_size, void* d_ws, size_t ws_size,
                              hipStream_t stream) {
  const float* x       = (const float*)d_in[0];   // (8,2048,4096) fp32
  const int*   trellis = (const int*)d_in[1];     // (65536,32) int32
  const float* tlut    = (const float*)d_in[2];   // (65536,2) fp32
  const float* SU      = (const float*)d_in[3];   // (4096,)
  const float* SV      = (const float*)d_in[4];   // (4096,)
  float* out = (float*)d_out;

  char* ws = (char*)d_ws;
  float*          W  = (float*)ws;                            // 64 MiB fp32
  unsigned short* Mt = (unsigned short*)(ws + (64ull << 20)); // 32 MiB bf16 [N][K]
  unsigned short* xb = (unsigned short*)(ws + (96ull << 20)); // 128 MiB bf16 [M][K]

  hipFuncSetAttribute(reinterpret_cast<const void*>(&k_gemm8),
                      hipFuncAttributeMaxDynamicSharedMemorySize, 131072);

  hipLaunchKernelGGL(k_deq_col1,  dim3(4096),  dim3(256), 0, stream, trellis, tlut, W);
  hipLaunchKernelGGL(k_fwht_row,  dim3(4096),  dim3(256), 0, stream, W);
  hipLaunchKernelGGL(k_fwht_col2, dim3(4096),  dim3(256), 0, stream, W, SU, SV, Mt);
  hipLaunchKernelGGL(k_cvt_x,     dim3(2048),  dim3(256), 0, stream, x, xb);
  hipLaunchKernelGGL(k_gemm8,     dim3(1024),  dim3(512), 131072, stream, xb, Mt, out);
}

// Round 10
// 648.435 us; speedup vs baseline: 6.6332x; 1.0399x over previous
//
#include <hip/hip_runtime.h>

// ---------- types ----------
typedef __attribute__((ext_vector_type(8))) short short8;   // 8 bf16 (4 VGPRs)
typedef __attribute__((ext_vector_type(4))) float f32x4;    // MFMA accumulator

__device__ __forceinline__ unsigned short f2bf(float f) {
  union { float f; unsigned u; } x{f};
  unsigned r = x.u + 0x7FFFu + ((x.u >> 16) & 1u);  // round-to-nearest-even
  return (unsigned short)(r >> 16);
}

// async global->LDS, 16B per lane; LDS dest is wave-uniform base + lane*16
__device__ __forceinline__ void gload_lds16(const void* g, void* l) {
  __builtin_amdgcn_global_load_lds(
      (__attribute__((address_space(1))) void*)((unsigned long long)g),
      (__attribute__((address_space(3))) void*)(unsigned)((unsigned long long)l),
      16, 0, 0);
}

// 6-stage H64 butterfly over the first index of tile[64][64]
__device__ __forceinline__ void butterfly64(float (*tile)[64], int t) {
  const int c  = t & 63;
  const int pb = t >> 6;
#pragma unroll
  for (int h = 1; h < 64; h <<= 1) {
#pragma unroll
    for (int k = 0; k < 8; ++k) {
      const int p  = pb + (k << 2);
      const int j1 = ((p & ~(h - 1)) << 1) | (p & (h - 1));
      const int j2 = j1 + h;
      const float a = tile[j1][c], b = tile[j2][c];
      tile[j1][c] = a + b;
      tile[j2][c] = a - b;
    }
    __syncthreads();
  }
}

// ---------- K1: fused trellis decode + col-FWHT(low 6 bits of o) -> W[4096][4096] ----------
__global__ void k_deq_col1(const int* __restrict__ trellis,
                           const float* __restrict__ tlut,
                           float* __restrict__ W) {
  __shared__ unsigned short words[16][32];   // 16 tiles * 32 words
  __shared__ float tile[64][64];
  const int t  = threadIdx.x;
  const int rg = blockIdx.x >> 6;            // o-group (64 rows)
  const int cg = blockIdx.x & 63;            // i-group (64 cols)
#pragma unroll
  for (int r = 0; r < 2; ++r) {
    const int ff = t + (r << 8);
    const int a = ff >> 7, rw = ff & 127;
    const int src = ((rg * 4 + a) * 256 + cg * 4) * 32 + rw;
    ((unsigned short*)words)[a * 128 + rw] = (unsigned short)(trellis[src] & 0xFFFF);
  }
  __syncthreads();
#pragma unroll
  for (int r = 0; r < 8; ++r) {
    const int f  = t + (r << 8);
    const int tl = f >> 7, s = f & 127;
    const unsigned short* w = words[tl];
    unsigned state = 0;
#pragma unroll
    for (int j = 0; j < 4; ++j) {
      const int ss = (s - j) & 127;
      state |= (((unsigned)w[ss >> 2] >> (12 - 4 * (ss & 3))) & 0xFu) << (4 * j);
    }
    const float2 v = *(const float2*)(tlut + (size_t)state * 2);
    const int o = ((tl >> 2) << 4) + (s >> 3);
    const int i = ((tl & 3) << 4) + ((s & 7) << 1);
    tile[o][i]     = v.x;
    tile[o][i + 1] = v.y;
  }
  __syncthreads();
  butterfly64(tile, t);
  const size_t base = ((size_t)(rg * 64)) * 4096 + cg * 64;
#pragma unroll
  for (int k = 0; k < 4; ++k) {
    const int idx = t + (k << 8);
    const int r = idx >> 4, c4 = idx & 15;
    *(float4*)(W + base + (size_t)r * 4096 + (c4 << 2)) = *(float4*)(&tile[r][c4 << 2]);
  }
}

// ---------- K2: FWHT over rows (i axis, full H4096), in place, * 1/64 ----------
__global__ void k_fwht_row(float* __restrict__ W) {
  __shared__ float row[4096];
  const int t = threadIdx.x;
  float* g = W + ((size_t)blockIdx.x << 12);
#pragma unroll
  for (int k = 0; k < 4; ++k) {
    const int e = (t + (k << 8)) << 2;
    *(float4*)(row + e) = *(const float4*)(g + e);
  }
  __syncthreads();
  for (int h = 1; h < 4096; h <<= 1) {
#pragma unroll
    for (int k = 0; k < 8; ++k) {
      const int p  = t + (k << 8);
      const int j1 = ((p & ~(h - 1)) << 1) | (p & (h - 1));
      const int j2 = j1 + h;
      const float a = row[j1], b = row[j2];
      row[j1] = a + b;
      row[j2] = a - b;
    }
    __syncthreads();
  }
#pragma unroll
  for (int k = 0; k < 4; ++k) {
    const int e = (t + (k << 8)) << 2;
    float4 v = *(float4*)(row + e);
    v.x *= 0.015625f; v.y *= 0.015625f; v.z *= 0.015625f; v.w *= 0.015625f;
    *(float4*)(g + e) = v;
  }
}

// ---------- K3: col FWHT, high 6 bits of o, *1/64, *SV[o]*SU[i], -> bf16 Mt[N][K] ----------
__global__ void k_fwht_col2(const float* __restrict__ W,
                            const float* __restrict__ SU,
                            const float* __restrict__ SV,
                            unsigned short* __restrict__ Mt) {
  __shared__ float tile[64][64];
  const int t  = threadIdx.x;
  const int b  = blockIdx.x >> 6;   // row residue (low bits)
  const int cg = blockIdx.x & 63;
#pragma unroll
  for (int k = 0; k < 4; ++k) {
    const int idx = t + (k << 8);
    const int a = idx >> 4, c4 = idx & 15;
    const int row = (a << 6) + b;
    *(float4*)(&tile[a][c4 << 2]) =
        *(const float4*)(W + (size_t)row * 4096 + ((size_t)cg << 6) + (c4 << 2));
  }
  __syncthreads();
  butterfly64(tile, t);
#pragma unroll
  for (int k = 0; k < 4; ++k) {
    const int idx = t + (k << 8);
    const int a = idx >> 4, c4 = idx & 15;
    const int row = (a << 6) + b;                 // o (OUT index)
    const int col0 = (cg << 6) + (c4 << 2);       // i (IN index)
    const float sv = SV[row] * 0.015625f;
    const float4 su = *(const float4*)(SU + col0);
    const float4 v = *(float4*)(&tile[a][c4 << 2]);
    ushort4 o;
    o.x = f2bf(v.x * sv * su.x);
    o.y = f2bf(v.y * sv * su.y);
    o.z = f2bf(v.z * sv * su.z);
    o.w = f2bf(v.w * sv * su.w);
    *(ushort4*)(Mt + (size_t)row * 4096 + col0) = o;
  }
}

// ---------- K4: x fp32 -> bf16 ----------
__global__ void k_cvt_x(const float* __restrict__ x, unsigned short* __restrict__ xb) {
  const long long n4 = (long long)16384 * 4096 / 4;
  long long i = (long long)blockIdx.x * blockDim.x + threadIdx.x;
  const long long stride = (long long)gridDim.x * blockDim.x;
  for (; i < n4; i += stride) {
    const float4 v = *(const float4*)(x + i * 4);
    ushort4 o;
    o.x = f2bf(v.x); o.y = f2bf(v.y); o.z = f2bf(v.z); o.w = f2bf(v.w);
    *(ushort4*)(xb + i * 4) = o;
  }
}

// ---------- K5: 256x256 GEMM, BK=32 QUAD-BUFFER, 3-tile-deep prefetch ----------
// Hypothesis: the 474us plateau (MfmaUtil 54% across 6 schedules) is staging
// LATENCY exposure: dbuf BK=64 gives only ~1100cyc of prefetch lead ~ HBM miss
// latency (~900cyc), so waves stall at the vmcnt gate every tile. Quad-buffer
// BK=32 (4 x 32KiB = same 128KiB LDS) gives ~3 tile-times (>3500cyc) of lead.
// Counted gate: vmcnt(8) leaves the 2 newer tiles' 8 loads in flight (m135:
// oldest-first retirement); tail tiles gate 8->4->0. Free-run K-tile skeleton
// (R6, proven WAR-safe: all reads of tile j-1 retired before the barrier at
// tile j; staging into buf (j+3)&3 issued after). 16x16x32 MFMA (32x32 shape
// regressed: wrong-geometry swizzle, 5e7 conflicts). Swizzle = R1's measured
// conflict-free BK=32 pattern: store c^((row>>1)&3) via pre-swizzled global
// source (linear LDS dest), read chunk q^((lr>>1)&3).
#define BARRIER __builtin_amdgcn_s_barrier()

#define STAGE(buf, jj) do { \
  const unsigned short* aJ = aRow + ((jj) << 5); \
  const unsigned short* bJ = bRow + ((jj) << 5); \
  gload_lds16(aJ,                  smem +         (buf)*16384 +        w1k); \
  gload_lds16(aJ + (128ull << 12), smem +         (buf)*16384 + 8192 + w1k); \
  gload_lds16(bJ,                  smem + 65536 + (buf)*16384 +        w1k); \
  gload_lds16(bJ + (128ull << 12), smem + 65536 + (buf)*16384 + 8192 + w1k); \
} while (0)

#define RD_AB(buf) do { _Pragma("unroll") \
  for (int ni = 0; ni < 4; ++ni) \
    bb[ni] = *(const short8*)(smem + 65536 + (buf)*16384 + wc4k + ni*1024 + cx); \
  _Pragma("unroll") \
  for (int mi = 0; mi < 8; ++mi) \
    af[mi] = *(const short8*)(smem +         (buf)*16384 + wr8k + mi*1024 + cx); \
} while (0)

#define MMA32 do { _Pragma("unroll") \
  for (int mi = 0; mi < 8; ++mi) { \
    acc[mi][0] = __builtin_amdgcn_mfma_f32_16x16x32_bf16(af[mi], bb[0], acc[mi][0], 0, 0, 0); \
    acc[mi][1] = __builtin_amdgcn_mfma_f32_16x16x32_bf16(af[mi], bb[1], acc[mi][1], 0, 0, 0); \
    acc[mi][2] = __builtin_amdgcn_mfma_f32_16x16x32_bf16(af[mi], bb[2], acc[mi][2], 0, 0, 0); \
    acc[mi][3] = __builtin_amdgcn_mfma_f32_16x16x32_bf16(af[mi], bb[3], acc[mi][3], 0, 0, 0); \
  } } while (0)

#define KT(buf, STAGES, WN) do { \
  asm volatile("s_waitcnt vmcnt(" #WN ")" ::: "memory"); \
  BARRIER; \
  STAGES; \
  RD_AB(buf); \
  __builtin_amdgcn_s_setprio(1); MMA32; __builtin_amdgcn_s_setprio(0); \
} while (0)

__global__ void __launch_bounds__(512, 2)
k_gemm8(const unsigned short* __restrict__ A,
        const unsigned short* __restrict__ B,
        float* __restrict__ C) {
  extern __shared__ char smem[];
  const int t    = threadIdx.x;
  const int lane = t & 63, w = t >> 6;
  const int wr   = w >> 2, wc = w & 3;          // 2 x 4 wave grid (128x64 tiles)
  const int lr   = lane & 15, q = lane >> 4;
  const int w1k  = w * 1024;
  const int wr8k = wr * 8192, wc4k = wc * 4096;

  const int nt = blockIdx.x & 15;               // 16 N-tiles
  const int mt = blockIdx.x >> 4;               // 64 M-tiles

  // frag read offset within a 256-row [r][64B] region: r*64 + ((q^((lr>>1)&3))<<4)
  const int cx = lr * 64 + ((q ^ ((lr >> 1) & 3)) << 4);

  // staging source: row = t>>2 (+128 for inst2), chunk pre-swizzled c^((row>>1)&3)
  const int srow  = t >> 2;
  const int csrc8 = (((t & 3) ^ ((t >> 3) & 3)) << 3);
  const unsigned short* aRow = A + (((size_t)(mt * 256 + srow)) << 12) + csrc8;
  const unsigned short* bRow = B + (((size_t)(nt * 256 + srow)) << 12) + csrc8;

  short8 af[8], bb[4];
  f32x4  acc[8][4];
#pragma unroll
  for (int i = 0; i < 8; ++i)
#pragma unroll
    for (int j = 0; j < 4; ++j) acc[i][j] = (f32x4){0.f, 0.f, 0.f, 0.f};

  // prologue: stage K-tiles 0,1,2 into bufs 0,1,2 (12 loads in flight)
  STAGE(0, 0); STAGE(1, 1); STAGE(2, 2);

  // 128 K-tiles of 32; tile j uses buf j&3; stage j+3 into buf (j+3)&3
  for (int g = 0; g < 31; ++g) {
    const int j = 4 * g;
    KT(0, STAGE(3, j + 3), 8);
    KT(1, STAGE(0, j + 4), 8);
    KT(2, STAGE(1, j + 5), 8);
    KT(3, STAGE(2, j + 6), 8);
  }
  // peeled tail: tiles 124..127 (stage only tile 127)
  KT(0, STAGE(3, 127), 8);
  KT(1, {},            8);
  KT(2, {},            4);
  KT(3, {},            0);

  // epilogue: C/D layout col=lane&15, row=(lane>>4)*4+reg
  float* cbase = C + (((size_t)(mt * 256 + wr * 128 + q * 4)) << 12)
               + nt * 256 + wc * 64 + lr;
#pragma unroll
  for (int mi = 0; mi < 8; ++mi)
#pragma unroll
    for (int ni = 0; ni < 4; ++ni)
#pragma unroll
      for (int r = 0; r < 4; ++r)
        cbase[(((size_t)(mi * 16 + r)) << 12) + ni * 16] = acc[mi][ni][r];
}

extern "C" void kernel_launch(void* const* d_in, const int* in_sizes, int n_in,
                              void* d_out, int out_size, void* d_ws, size_t ws_size,
                              hipStream_t stream) {
  const float* x       = (const float*)d_in[0];   // (8,2048,4096) fp32
  const int*   trellis = (const int*)d_in[1];     // (65536,32) int32
  const float* tlut    = (const float*)d_in[2];   // (65536,2) fp32
  const float* SU      = (const float*)d_in[3];   // (4096,)
  const float* SV      = (const float*)d_in[4];   // (4096,)
  float* out = (float*)d_out;

  char* ws = (char*)d_ws;
  float*          W  = (float*)ws;                            // 64 MiB fp32
  unsigned short* Mt = (unsigned short*)(ws + (64ull << 20)); // 32 MiB bf16 [N][K]
  unsigned short* xb = (unsigned short*)(ws + (96ull << 20)); // 128 MiB bf16 [M][K]

  hipFuncSetAttribute(reinterpret_cast<const void*>(&k_gemm8),
                      hipFuncAttributeMaxDynamicSharedMemorySize, 131072);

  hipLaunchKernelGGL(k_deq_col1,  dim3(4096),  dim3(256), 0, stream, trellis, tlut, W);
  hipLaunchKernelGGL(k_fwht_row,  dim3(4096),  dim3(256), 0, stream, W);
  hipLaunchKernelGGL(k_fwht_col2, dim3(4096),  dim3(256), 0, stream, W, SU, SV, Mt);
  hipLaunchKernelGGL(k_cvt_x,     dim3(2048),  dim3(256), 0, stream, x, xb);
  hipLaunchKernelGGL(k_gemm8,     dim3(1024),  dim3(512), 131072, stream, xb, Mt, out);
}